// Round 13
// baseline (723.280 us; speedup 1.0000x reference)
//
#include <hip/hip_runtime.h>
#include <cstdint>
#include <math.h>

typedef unsigned int u32;
typedef unsigned long long u64;
typedef __attribute__((ext_vector_type(8))) short short8v;   // 8 bf16 (4 VGPR)
typedef __attribute__((ext_vector_type(4))) float f32x4;     // MFMA acc

// ---------------- geometry ----------------
#define N_BATCH 8
#define C_IN    512
#define PX      2500     // 50*50
#define KDIM    4608     // 512*9
#define NA      22500
#define PRE_NMS 6000
#define POST_NMS 300

// d_out float layout (reference tuple concatenated):
// rpn_locs   [8][22500][4]  @ 0        (720000)
// rpn_scores [8][22500][2]  @ 720000   (360000)
// anchors    [22500][4]     @ 1080000  (90000)
// rois       [300][4]       @ 1170000  (1200)
#define OUT_SCORES 720000
#define OUT_ANCH   1080000
#define OUT_ROIS   1170000

// ws layout (float offsets)
#define WS_X     0            // x: 8*512*2500 floats (post-relu conv out)
#define WS_SCORE 10240000     // 22500
#define WS_BOX   10262500     // 22500*4
#define WS_LIST  10352500     // u64[8192] = 16384 floats (8B aligned)
#define WS_META  10388500     // ints (16)
#define WS_WP    10388608     // packed split W: 512*4608 u32 = 2,359,296
#define WS_XP    12747904     // packed split X: 8*512*2500 u32 = 10,240,000 (total ~92 MB)
#define WS_END   22987904

#define NW_ELEMS (512 * KDIM)          // 2,359,296
#define NX_ELEMS (N_BATCH * C_IN * PX) // 10,240,000

// ---------- RNE bf16 split: hi=RNE(f), lo=RNE(f - hi); pair error ~2^-18 rel ----------
__device__ inline u32 rne_hi16(float f) {
    u32 u = __float_as_uint(f);
    return (u + 0x7FFFu + ((u >> 16) & 1u)) >> 16;
}
__device__ inline u32 pack_split(float f) {
    u32 rh  = rne_hi16(f);
    float d = f - __uint_as_float(rh << 16);
    u32 rl  = rne_hi16(d);
    return (rh << 16) | rl;
}

// =================== prep: split W ([co][cig][r][ci32] layout) + split X ===================
__global__ __launch_bounds__(256) void k_prep(const float* __restrict__ Wc,
                                              const float* __restrict__ in,
                                              u32* __restrict__ WP,
                                              u32* __restrict__ XP) {
    int o = blockIdx.x * 256 + threadIdx.x;
    if (o < NW_ELEMS) {
        int ci_in = o & 31;
        int tmp   = o >> 5;           // co*144 + cig*9 + r
        int r     = tmp % 9;
        int cc    = tmp / 9;          // co*16 + cig
        int co    = cc >> 4;
        int cig   = cc & 15;
        int ci    = cig * 32 + ci_in;
        WP[o] = pack_split(Wc[(size_t)co * KDIM + ci * 9 + r]);
    } else {
        int o2 = o - NW_ELEMS;
        if (o2 < NX_ELEMS && XP) XP[o2] = pack_split(in[o2]);
    }
}

// =================== conv3x3 + bias + relu : bf16x3-split MFMA implicit GEMM ===================
// 128co x 64px tiles, grid 1280 = exactly 5 blocks/CU (occupancy was grid-limited at 640).
// Same kstep order / split values / per-element MFMA chain as round 10 -> bit-identical output.
__global__ __launch_bounds__(256) void k_conv3(const float* __restrict__ in,
                                               const u32* __restrict__ XP,
                                               const u32* __restrict__ WP,
                                               const float* __restrict__ bc,
                                               float* __restrict__ xout) {
    __shared__ u32 Ap[128][32];   // [co][k] packed, swizzled  (16 KB)
    __shared__ u32 Bp[64][32];    // [px][k] packed, swizzled  (8 KB)

    int b  = blockIdx.x;
    int n  = b & 7;               // batch -> XCD
    int q  = b >> 3;              // 0..159
    int cb = q & 3;               // co tile (4)
    int pt = q >> 2;              // 0..39 px tile of 64
    int t  = threadIdx.x;
    int lane = t & 63;
    int w  = t >> 6;
    int wr = w >> 1, wc = w & 1;  // wave -> (co half 64, px half 32)
    int px0 = pt * 64, co0 = cb * 128;
    const float* inN = in + (size_t)n * C_IN * PX;
    const u32*   XPn = XP ? (XP + (size_t)n * C_IN * PX) : nullptr;

    // staging roles
    int sco = t >> 1;                 // A: co 0..127
    int skb = (t & 1) << 4;           // A: k offset 0/16
    int spx = t & 63;                 // B: px 0..63
    int skk = (t >> 6) << 3;          // B: k offset 0/8/16/24
    int gpx = px0 + spx;
    int sy  = gpx / 50;
    int sx  = gpx - sy * 50;
    bool pxok = (gpx < PX);
    const u32* wpA = WP + (size_t)(co0 + sco) * KDIM + skb;

    f32x4 acc[4][2];
#pragma unroll
    for (int i = 0; i < 4; ++i)
#pragma unroll
        for (int j = 0; j < 2; ++j) acc[i][j] = (f32x4)0.f;

    const int ro  = lane & 15;
    const int g8s = (lane >> 4) << 1;

    for (int cig = 0; cig < 16; ++cig) {
        int ci0 = cig << 5;
        for (int r = 0; r < 9; ++r) {
            int kstep = cig * 9 + r;
            // ---- stage A: packed W, swizzled slots ----
            {
                const u32* wp = wpA + kstep * 32;
                int rs = sco & 7;
#pragma unroll
                for (int qq = 0; qq < 4; ++qq) {
                    uint4 wv = *(const uint4*)(wp + qq * 4);
                    int slot = ((skb >> 2) + qq) ^ rs;
                    *(uint4*)&Ap[sco][slot << 2] = wv;
                }
            }
            // ---- stage B: im2col gather (packed), 8 k per thread, swizzled ----
            {
                int ry = (r * 11) >> 5;
                int dy = ry - 1;
                int dx = r - ry * 3 - 1;
                int iy = sy + dy, ix = sx + dx;
                bool valid = pxok && ((unsigned)iy < 50u) && ((unsigned)ix < 50u);
                int off = iy * 50 + ix;
                u32 uu[8];
                if (XPn) {
                    const u32* bp = XPn + (size_t)(ci0 + skk) * PX + off;
#pragma unroll
                    for (int it = 0; it < 8; ++it)
                        uu[it] = valid ? bp[it * PX] : 0u;
                } else {
                    const float* bp = inN + (size_t)(ci0 + skk) * PX + off;
#pragma unroll
                    for (int it = 0; it < 8; ++it)
                        uu[it] = valid ? pack_split(bp[it * PX]) : 0u;
                }
                int rs = spx & 7;
#pragma unroll
                for (int qq = 0; qq < 2; ++qq) {
                    int slot = ((skk >> 2) + qq) ^ rs;
                    *(uint4*)&Bp[spx][slot << 2] = *(uint4*)&uu[qq * 4];
                }
            }
            __syncthreads();

            // ---- fragments: swizzled b128 reads + v_perm unpack, 3-pass MFMA ----
            short8v aH[4], aL[4], bH[2], bL[2];
#pragma unroll
            for (int s = 0; s < 4; ++s) {
                int ra = wr * 64 + s * 16 + ro;
                int rs = ra & 7;
                u32 pa[8];
                *(uint4*)&pa[0] = *(const uint4*)&Ap[ra][(g8s ^ rs) << 2];
                *(uint4*)&pa[4] = *(const uint4*)&Ap[ra][((g8s + 1) ^ rs) << 2];
                u32 h[4], l[4];
#pragma unroll
                for (int w2 = 0; w2 < 4; ++w2) {
                    h[w2] = __builtin_amdgcn_perm(pa[2 * w2 + 1], pa[2 * w2], 0x07060302u);
                    l[w2] = __builtin_amdgcn_perm(pa[2 * w2 + 1], pa[2 * w2], 0x05040100u);
                }
                aH[s] = *(short8v*)h;
                aL[s] = *(short8v*)l;
            }
#pragma unroll
            for (int s = 0; s < 2; ++s) {
                int rb = wc * 32 + s * 16 + ro;
                int rs = rb & 7;
                u32 pb[8];
                *(uint4*)&pb[0] = *(const uint4*)&Bp[rb][(g8s ^ rs) << 2];
                *(uint4*)&pb[4] = *(const uint4*)&Bp[rb][((g8s + 1) ^ rs) << 2];
                u32 h[4], l[4];
#pragma unroll
                for (int w2 = 0; w2 < 4; ++w2) {
                    h[w2] = __builtin_amdgcn_perm(pb[2 * w2 + 1], pb[2 * w2], 0x07060302u);
                    l[w2] = __builtin_amdgcn_perm(pb[2 * w2 + 1], pb[2 * w2], 0x05040100u);
                }
                bH[s] = *(short8v*)h;
                bL[s] = *(short8v*)l;
            }
#pragma unroll
            for (int i = 0; i < 4; ++i)
#pragma unroll
                for (int j = 0; j < 2; ++j) {
                    acc[i][j] = __builtin_amdgcn_mfma_f32_16x16x32_bf16(aH[i], bH[j], acc[i][j], 0, 0, 0);
                    acc[i][j] = __builtin_amdgcn_mfma_f32_16x16x32_bf16(aH[i], bL[j], acc[i][j], 0, 0, 0);
                    acc[i][j] = __builtin_amdgcn_mfma_f32_16x16x32_bf16(aL[i], bH[j], acc[i][j], 0, 0, 0);
                }
            __syncthreads();
        }
    }

    // ---- epilogue: bias + relu, fp32 store ----
    int coB  = co0 + wr * 64;
    int pxB  = px0 + wc * 32 + ro;
    int rowg = (lane >> 4) << 2;
#pragma unroll
    for (int i = 0; i < 4; ++i) {
#pragma unroll
        for (int rg = 0; rg < 4; ++rg) {
            int co = coB + i * 16 + rowg + rg;
            float bias = bc[co];
            float* dst = xout + ((size_t)n * C_IN + co) * PX;
#pragma unroll
            for (int j = 0; j < 2; ++j) {
                int px = pxB + j * 16;
                if (px < PX) dst[px] = fmaxf(acc[i][j][rg] + bias, 0.f);
            }
        }
    }
}

__device__ inline float readDim(const void* p) {
    int v = *(const int*)p;
    if (v > 0 && v <= 100000) return (float)v;
    return *(const float*)p;
}

// =================== 1x1 heads GEMM (fp32) + fused decode for batch 0 ===================
__global__ __launch_bounds__(256) void k_heads(const float* __restrict__ x,
                                               const float* __restrict__ Wreg,
                                               const float* __restrict__ breg,
                                               const float* __restrict__ Wcls,
                                               const float* __restrict__ bcls,
                                               float* __restrict__ out,
                                               float* __restrict__ wsScore,
                                               float* __restrict__ wsBox,
                                               const void* pih, const void* piw) {
    __shared__ float As[32][68];
    __shared__ float Bs[32][68];
    __shared__ float Hs[54][64];     // staged head outputs for decode (batch 0)
    int b  = blockIdx.x;
    int pt = b % 40, n = b / 40;
    int t  = threadIdx.x;
    int tx = t & 7, ty = t >> 3;     // ty 0..31 -> 2 channels each; tx -> 8 px
    int px0 = pt * 64;
    float acc[2][8];
#pragma unroll
    for (int i = 0; i < 2; ++i)
#pragma unroll
        for (int j = 0; j < 8; ++j) acc[i][j] = 0.f;

    for (int k0 = 0; k0 < 512; k0 += 32) {
        {
            int c   = t >> 2;            // 0..63
            int kkb = (t & 3) << 3;
            const float* src = nullptr;
            if (c < 36)      src = Wreg + (size_t)c * 512 + k0 + kkb;
            else if (c < 54) src = Wcls + (size_t)(c - 36) * 512 + k0 + kkb;
#pragma unroll
            for (int qq = 0; qq < 2; ++qq) {
                float4 wv = src ? *(const float4*)(src + qq * 4) : make_float4(0, 0, 0, 0);
                As[kkb + qq * 4 + 0][c] = wv.x;
                As[kkb + qq * 4 + 1][c] = wv.y;
                As[kkb + qq * 4 + 2][c] = wv.z;
                As[kkb + qq * 4 + 3][c] = wv.w;
            }
        }
        {
            int pxl = t & 63;
            int kk0 = (t >> 6) << 3;     // 0,8,16,24
            int px  = px0 + pxl;
#pragma unroll
            for (int it = 0; it < 8; ++it) {
                int kk = kk0 + it;
                float v = 0.f;
                if (px < PX) v = x[((size_t)n * 512 + k0 + kk) * PX + px];
                Bs[kk][pxl] = v;
            }
        }
        __syncthreads();
#pragma unroll 8
        for (int kk = 0; kk < 32; ++kk) {
            float a0 = As[kk][ty * 2], a1 = As[kk][ty * 2 + 1];
            float bb[8];
            *(float4*)&bb[0] = *(const float4*)&Bs[kk][tx * 8];
            *(float4*)&bb[4] = *(const float4*)&Bs[kk][tx * 8 + 4];
#pragma unroll
            for (int j = 0; j < 8; ++j) {
                acc[0][j] = fmaf(a0, bb[j], acc[0][j]);
                acc[1][j] = fmaf(a1, bb[j], acc[1][j]);
            }
        }
        __syncthreads();
    }
    int pxb = px0 + tx * 8;
#pragma unroll
    for (int i = 0; i < 2; ++i) {
        int c = ty * 2 + i;
        if (c >= 54) continue;
        float bias = (c < 36) ? breg[c] : bcls[c - 36];
        for (int j = 0; j < 8; ++j) {
            int px = pxb + j;
            if (px >= PX) break;
            float v = acc[i][j] + bias;
            if (c < 36)
                out[(size_t)n * 90000 + (size_t)px * 36 + c] = v;
            else
                out[OUT_SCORES + (size_t)n * 45000 + (size_t)px * 18 + (c - 36)] = v;
            if (n == 0) Hs[c][tx * 8 + j] = v;
        }
    }

    // ---- fused decode + anchors for batch 0 ----
    if (n == 0) {
        __syncthreads();
        float imgH = readDim(pih), imgW = readDim(piw);
        const float ratios[3] = {0.5f, 1.f, 2.f};
        const float scales[3] = {8.f, 16.f, 32.f};
        for (int idx = t; idx < 64 * 9; idx += 256) {
            int pxl = idx / 9;
            int a   = idx - pxl * 9;
            int px  = px0 + pxl;
            if (px >= PX) continue;
            int gi = px * 9 + a;
            int y = px / 50, xq = px - y * 50;
            float r = ratios[a / 3], s = scales[a % 3];
            float hh = 16.f * s * sqrtf(r);
            float wv = 16.f * s * sqrtf(1.f / r);
            float ay1 = y * 16.f + 8.f - 0.5f * hh;
            float ax1 = xq * 16.f + 8.f - 0.5f * wv;
            float ay2 = y * 16.f + 8.f + 0.5f * hh;
            float ax2 = xq * 16.f + 8.f + 0.5f * wv;
            *(float4*)(out + OUT_ANCH + (size_t)gi * 4) = make_float4(ay1, ax1, ay2, ax2);

            float l0 = Hs[a * 4 + 0][pxl];
            float l1 = Hs[a * 4 + 1][pxl];
            float l2 = Hs[a * 4 + 2][pxl];
            float l3 = Hs[a * 4 + 3][pxl];
            float s0 = Hs[36 + 2 * a][pxl];
            float s1 = Hs[37 + 2 * a][pxl];
            float fg = 1.f / (1.f + expf(s0 - s1));
            float ah = ay2 - ay1, aw = ax2 - ax1;
            float acy = ay1 + 0.5f * ah, acx = ax1 + 0.5f * aw;
            float cy = l0 * ah + acy;
            float cx = l1 * aw + acx;
            float bh = expf(l2) * ah;
            float bw = expf(l3) * aw;
            float b0 = cy - 0.5f * bh, b1 = cx - 0.5f * bw;
            float b2 = cy + 0.5f * bh, b3 = cx + 0.5f * bw;
            b0 = fminf(fmaxf(b0, 0.f), imgH);
            b1 = fminf(fmaxf(b1, 0.f), imgW);
            b2 = fminf(fmaxf(b2, 0.f), imgH);
            b3 = fminf(fmaxf(b3, 0.f), imgW);
            bool valid = ((b2 - b0) >= 16.f) && ((b3 - b1) >= 16.f);
            wsScore[gi] = valid ? fg : -INFINITY;
            *(float4*)(wsBox + (size_t)gi * 4) = make_float4(b0, b1, b2, b3);
        }
    }
}

// =================== select: top-6000 threshold + compaction -> global list ===================
__device__ inline u32 fkey(float s) {
    u32 u = __float_as_uint(s);
    return (u & 0x80000000u) ? ~u : (u | 0x80000000u);
}

__global__ __launch_bounds__(1024) void k_select(const float* __restrict__ score,
                                                 u64* __restrict__ list,
                                                 int* __restrict__ meta) {
    __shared__ u32 hist[4096];
    __shared__ int sB1, sB2, sM3, sNeed, sV;
    __shared__ u32 sT32;
    __shared__ int cHi, cTie;
    int t = threadIdx.x;
    const int NT = 1024;

    // ---- pass 1: top 12 bits ----
    for (int i = t; i < 4096; i += NT) hist[i] = 0;
    __syncthreads();
    for (int i = t; i < NA; i += NT) atomicAdd(&hist[fkey(score[i]) >> 20], 1u);
    __syncthreads();
    for (int off = 1; off < 4096; off <<= 1) {
        u32 v[4]; int c = 0;
        for (int bb = t; bb < 4096; bb += NT) { v[c++] = hist[bb] + ((bb + off < 4096) ? hist[bb + off] : 0u); }
        __syncthreads();
        c = 0;
        for (int bb = t; bb < 4096; bb += NT) hist[bb] = v[c++];
        __syncthreads();
    }
    for (int bb = t; bb < 4096; bb += NT) {
        u32 Sb  = hist[bb];
        u32 Sb1 = (bb < 4095) ? hist[bb + 1] : 0u;
        if (Sb >= PRE_NMS && Sb1 < PRE_NMS) sB1 = bb;
    }
    if (t == 0) sV = (int)hist[2048];
    __syncthreads();
    int B1 = sB1;
    int m1 = (B1 < 4095) ? (int)hist[B1 + 1] : 0;
    int V  = sV;
    __syncthreads();

    // ---- pass 2: mid 12 bits ----
    for (int i = t; i < 4096; i += NT) hist[i] = 0;
    __syncthreads();
    for (int i = t; i < NA; i += NT) {
        u32 key = fkey(score[i]);
        if ((int)(key >> 20) == B1) atomicAdd(&hist[(key >> 8) & 0xFFFu], 1u);
    }
    __syncthreads();
    for (int off = 1; off < 4096; off <<= 1) {
        u32 v[4]; int c = 0;
        for (int bb = t; bb < 4096; bb += NT) { v[c++] = hist[bb] + ((bb + off < 4096) ? hist[bb + off] : 0u); }
        __syncthreads();
        c = 0;
        for (int bb = t; bb < 4096; bb += NT) hist[bb] = v[c++];
        __syncthreads();
    }
    for (int bb = t; bb < 4096; bb += NT) {
        int Sb  = m1 + (int)hist[bb];
        int Sb1 = m1 + (int)((bb < 4095) ? hist[bb + 1] : 0u);
        if (Sb >= PRE_NMS && Sb1 < PRE_NMS) sB2 = bb;
    }
    __syncthreads();
    int B2 = sB2;
    int m2 = m1 + (int)((B2 < 4095) ? hist[B2 + 1] : 0u);
    u32 P24 = ((u32)B1 << 12) | (u32)B2;
    __syncthreads();

    // ---- pass 3: low 8 bits ----
    for (int i = t; i < 256; i += NT) hist[i] = 0;
    __syncthreads();
    for (int i = t; i < NA; i += NT) {
        u32 key = fkey(score[i]);
        if ((key >> 8) == P24) atomicAdd(&hist[key & 0xFFu], 1u);
    }
    __syncthreads();
    for (int off = 1; off < 256; off <<= 1) {
        u32 v[1]; int c = 0;
        for (int bb = t; bb < 256; bb += NT) { v[c++] = hist[bb] + ((bb + off < 256) ? hist[bb + off] : 0u); }
        __syncthreads();
        c = 0;
        for (int bb = t; bb < 256; bb += NT) hist[bb] = v[c++];
        __syncthreads();
    }
    for (int bb = t; bb < 256; bb += NT) {
        int Sb  = m2 + (int)hist[bb];
        int Sb1 = m2 + (int)((bb < 255) ? hist[bb + 1] : 0u);
        if (Sb >= PRE_NMS && Sb1 < PRE_NMS) {
            sM3   = m2 + (int)((bb < 255) ? hist[bb + 1] : 0u);
            sNeed = PRE_NMS - sM3;
            sT32  = (P24 << 8) | (u32)bb;
        }
    }
    if (t == 0) { cHi = 0; cTie = 0; meta[0] = (V < PRE_NMS) ? V : PRE_NMS; }
    __syncthreads();
    int m3 = sM3, need = sNeed;
    u32 T32 = sT32;

    // ---- compaction -> global list[0..5999]; pad 6000..8191 with 0 ----
    for (int i = t; i < NA; i += NT) {
        u32 key = fkey(score[i]);
        u64 comp = ((u64)key << 32) | (u64)(0xFFFFFFFFu - (u32)i);
        if (key > T32) {
            int p = atomicAdd(&cHi, 1);
            list[p] = comp;
        } else if (key == T32) {
            int p = atomicAdd(&cTie, 1);
            if (p < need) list[m3 + p] = comp;
        }
    }
    for (int i = PRE_NMS + t; i < 8192; i += NT) list[i] = 0ull;
}

// =================== presort: 4 blocks each bitonic-sort a 2048-chunk (k=2..2048) ===================
__global__ __launch_bounds__(1024) void k_presort(u64* __restrict__ list) {
    __shared__ u64 ls[2048];
    int t    = threadIdx.x;
    int base = blockIdx.x << 11;
    ls[t] = list[base + t];
    ls[t + 1024] = list[base + t + 1024];
    __syncthreads();
    for (int k = 2; k <= 2048; k <<= 1) {
        for (int j = k >> 1; j > 0; j >>= 1) {
            for (int i = t; i < 2048; i += 1024) {
                int ixj = i ^ j;
                if (ixj > i) {
                    u64 a = ls[i], b2 = ls[ixj];
                    bool desc = (((base + i) & k) == 0);
                    if (desc ? (a < b2) : (a > b2)) { ls[i] = b2; ls[ixj] = a; }
                }
            }
            __syncthreads();
        }
    }
    list[base + t] = ls[t];
    list[base + t + 1024] = ls[t + 1024];
}

// =================== merge (k=4096,8192) + greedy NMS, 128-wide chunks ===================
__global__ __launch_bounds__(1024) void k_mergenms(const u64* __restrict__ list,
                                                   const float* __restrict__ boxes,
                                                   const int* __restrict__ meta,
                                                   float* __restrict__ rois) {
    __shared__ u64 sb[8192];
    __shared__ float kb[POST_NMS][4];
    __shared__ float cb4[128][4];
    __shared__ u32 Kw[128][4];       // kill bits: words 0..3 cover j=0..127
    __shared__ u32 supA[128];
    __shared__ int sKept;
    int t = threadIdx.x;
    const int NT = 1024;

    for (int i = t; i < 8192; i += NT) sb[i] = list[i];
    __syncthreads();

    // remaining bitonic phases
    for (int k = 4096; k <= 8192; k <<= 1) {
        for (int j = k >> 1; j > 0; j >>= 1) {
            for (int i = t; i < 8192; i += NT) {
                int ixj = i ^ j;
                if (ixj > i) {
                    u64 a = sb[i], bv = sb[ixj];
                    bool desc = ((i & k) == 0);
                    if (desc ? (a < bv) : (a > bv)) { sb[i] = bv; sb[ixj] = a; }
                }
            }
            __syncthreads();
        }
    }

    int keepN = meta[0];
    if (t == 0) sKept = 0;
    __syncthreads();

    int s = t >> 3, g = t & 7;   // 128 cands x 8 groups
    for (int c0 = 0; c0 < PRE_NMS; c0 += 128) {
        if (sKept >= POST_NMS) break;
        // load 128 candidate boxes
        if (t < 128) {
            u32 bidx = 0xFFFFFFFFu - (u32)sb[c0 + t];
            if (bidx >= NA) bidx = 0;            // pad-safe
            float4 bx = *(const float4*)(boxes + (size_t)bidx * 4);
            cb4[t][0] = bx.x; cb4[t][1] = bx.y; cb4[t][2] = bx.z; cb4[t][3] = bx.w;
            Kw[t][0] = 0; Kw[t][1] = 0; Kw[t][2] = 0; Kw[t][3] = 0;
            supA[t] = 0;
        }
        __syncthreads();

        float y1 = cb4[s][0], x1 = cb4[s][1], y2 = cb4[s][2], x2 = cb4[s][3];
        float area = (y2 - y1) * (x2 - x1);

        // pairwise kill bits: this thread covers j = g*16 .. g*16+15 (one u32 half-word range)
        u32 kbits = 0;
#pragma unroll
        for (int qq = 0; qq < 16; ++qq) {
            int j = g * 16 + qq;
            if (j > s) {
                float jy1 = cb4[j][0], jx1 = cb4[j][1], jy2 = cb4[j][2], jx2 = cb4[j][3];
                float yy1 = fmaxf(y1, jy1), xx1 = fmaxf(x1, jx1);
                float yy2 = fminf(y2, jy2), xx2 = fminf(x2, jx2);
                float inter = fmaxf(yy2 - yy1, 0.f) * fmaxf(xx2 - xx1, 0.f);
                float ja = (jy2 - jy1) * (jx2 - jx1);
                float iou = inter / (area + ja - inter + 1e-12f);
                if (iou > 0.7f) kbits |= 1u << (j & 31);
            }
        }
        if (kbits) atomicOr(&Kw[s][g >> 1], kbits);

        // phase A: cand s vs already-kept, split 8 ways
        int kept0 = sKept;
        bool supf = false;
        for (int jj = g; jj < kept0; jj += 8) {
            float ky1 = kb[jj][0], kx1 = kb[jj][1], ky2 = kb[jj][2], kx2 = kb[jj][3];
            float yy1 = fmaxf(ky1, y1), xx1 = fmaxf(kx1, x1);
            float yy2 = fminf(ky2, y2), xx2 = fminf(kx2, x2);
            float inter = fmaxf(yy2 - yy1, 0.f) * fmaxf(xx2 - xx1, 0.f);
            float karea = (ky2 - ky1) * (kx2 - kx1);
            float iou = inter / (karea + area - inter + 1e-12f);
            if (iou > 0.7f) { supf = true; break; }
        }
        if (supf) atomicOr(&supA[s], 1u);
        __syncthreads();

        // serial greedy over the 128-chunk (LDS reads only)
        if (t == 0) {
            u64 m0 = 0, m1 = 0;
            int kept = sKept;
            for (int s2 = 0; s2 < 128 && kept < POST_NMS; ++s2) {
                if (c0 + s2 >= keepN) continue;
                if (supA[s2]) continue;
                bool supm = (s2 < 64) ? ((m0 >> s2) & 1ull) : ((m1 >> (s2 - 64)) & 1ull);
                if (supm) continue;
                kb[kept][0] = cb4[s2][0]; kb[kept][1] = cb4[s2][1];
                kb[kept][2] = cb4[s2][2]; kb[kept][3] = cb4[s2][3];
                *(float4*)(rois + (size_t)kept * 4) =
                    make_float4(cb4[s2][0], cb4[s2][1], cb4[s2][2], cb4[s2][3]);
                kept++;
                m0 |= ((u64)Kw[s2][1] << 32) | (u64)Kw[s2][0];
                m1 |= ((u64)Kw[s2][3] << 32) | (u64)Kw[s2][2];
            }
            sKept = kept;
        }
        __syncthreads();
    }

    int kf = sKept;
    for (int r = kf * 4 + t; r < POST_NMS * 4; r += NT) rois[r] = 0.f;
}

// =================== launcher ===================
extern "C" void kernel_launch(void* const* d_in, const int* in_sizes, int n_in,
                              void* d_out, int out_size, void* d_ws, size_t ws_size,
                              hipStream_t stream) {
    const float* feat = (const float*)d_in[0];
    const float* Wc   = (const float*)d_in[1];
    const float* bc   = (const float*)d_in[2];
    const float* Wcls = (const float*)d_in[3];
    const float* bcls = (const float*)d_in[4];
    const float* Wreg = (const float*)d_in[5];
    const float* breg = (const float*)d_in[6];
    const void* pih   = d_in[7];
    const void* piw   = d_in[8];
    float* out = (float*)d_out;
    float* ws  = (float*)d_ws;

    u32* WP   = (u32*)(ws + WS_WP);
    u64* list = (u64*)(ws + WS_LIST);
    int* meta = (int*)(ws + WS_META);
    bool haveXP = (ws_size >= (size_t)WS_END * sizeof(float));
    u32* XP = haveXP ? (u32*)(ws + WS_XP) : nullptr;

    int prepItems = NW_ELEMS + (haveXP ? NX_ELEMS : 0);
    hipLaunchKernelGGL(k_prep, dim3((prepItems + 255) / 256), dim3(256), 0, stream, Wc, feat, WP, XP);
    hipLaunchKernelGGL(k_conv3, dim3(1280), dim3(256), 0, stream, feat, XP, WP, bc, ws + WS_X);
    hipLaunchKernelGGL(k_heads, dim3(320), dim3(256), 0, stream, ws + WS_X, Wreg, breg, Wcls, bcls,
                       out, ws + WS_SCORE, ws + WS_BOX, pih, piw);
    hipLaunchKernelGGL(k_select, dim3(1), dim3(1024), 0, stream, ws + WS_SCORE, list, meta);
    hipLaunchKernelGGL(k_presort, dim3(4), dim3(1024), 0, stream, list);
    hipLaunchKernelGGL(k_mergenms, dim3(1), dim3(1024), 0, stream, list, ws + WS_BOX, meta, out + OUT_ROIS);
}

// Round 14
// 616.968 us; speedup vs baseline: 1.1723x; 1.1723x over previous
//
#include <hip/hip_runtime.h>
#include <cstdint>
#include <math.h>

typedef unsigned int u32;
typedef unsigned long long u64;
typedef __attribute__((ext_vector_type(8))) short short8v;   // 8 bf16 (4 VGPR)
typedef __attribute__((ext_vector_type(4))) float f32x4;     // MFMA acc

// ---------------- geometry ----------------
#define N_BATCH 8
#define C_IN    512
#define PX      2500     // 50*50
#define KDIM    4608     // 512*9
#define NA      22500
#define PRE_NMS 6000
#define POST_NMS 300

// d_out float layout (reference tuple concatenated):
// rpn_locs   [8][22500][4]  @ 0        (720000)
// rpn_scores [8][22500][2]  @ 720000   (360000)
// anchors    [22500][4]     @ 1080000  (90000)
// rois       [300][4]       @ 1170000  (1200)
#define OUT_SCORES 720000
#define OUT_ANCH   1080000
#define OUT_ROIS   1170000

// ws layout (float offsets)
#define WS_X     0            // x: 8*512*2500 floats (post-relu conv out)
#define WS_SCORE 10240000     // 22500
#define WS_BOX   10262500     // 22500*4
#define WS_LIST  10352500     // u64[8192] = 16384 floats (8B aligned)
#define WS_META  10388500     // ints (16)
#define WS_WP    10388608     // packed split W: 512*4608 u32 = 2,359,296
#define WS_XP    12747904     // packed split X: 8*512*2500 u32 = 10,240,000 (total ~92 MB)
#define WS_END   22987904

#define NW_ELEMS (512 * KDIM)          // 2,359,296
#define NX_ELEMS (N_BATCH * C_IN * PX) // 10,240,000

// ---------- RNE bf16 split: hi=RNE(f), lo=RNE(f - hi); pair error ~2^-18 rel ----------
__device__ inline u32 rne_hi16(float f) {
    u32 u = __float_as_uint(f);
    return (u + 0x7FFFu + ((u >> 16) & 1u)) >> 16;
}
__device__ inline u32 pack_split(float f) {
    u32 rh  = rne_hi16(f);
    float d = f - __uint_as_float(rh << 16);
    u32 rl  = rne_hi16(d);
    return (rh << 16) | rl;
}

// =================== prep: split W ([co][cig][r][ci32] layout) + split X ===================
__global__ __launch_bounds__(256) void k_prep(const float* __restrict__ Wc,
                                              const float* __restrict__ in,
                                              u32* __restrict__ WP,
                                              u32* __restrict__ XP) {
    int o = blockIdx.x * 256 + threadIdx.x;
    if (o < NW_ELEMS) {
        int ci_in = o & 31;
        int tmp   = o >> 5;           // co*144 + cig*9 + r
        int r     = tmp % 9;
        int cc    = tmp / 9;          // co*16 + cig
        int co    = cc >> 4;
        int cig   = cc & 15;
        int ci    = cig * 32 + ci_in;
        WP[o] = pack_split(Wc[(size_t)co * KDIM + ci * 9 + r]);
    } else {
        int o2 = o - NW_ELEMS;
        if (o2 < NX_ELEMS && XP) XP[o2] = pack_split(in[o2]);
    }
}

// =================== conv3x3 + bias + relu : bf16x3-split MFMA implicit GEMM ===================
// Packed-u32 LDS (hi|lo bf16 per k-elem), XOR slot swizzle. At m97-structure ceiling (~35% MfmaUtil).
// Measured A/B: BK=64 pairing (r11) and 64px tile (r13) both regress -> this is the local optimum.
__global__ __launch_bounds__(256) void k_conv3(const float* __restrict__ in,
                                               const u32* __restrict__ XP,
                                               const u32* __restrict__ WP,
                                               const float* __restrict__ bc,
                                               float* __restrict__ xout) {
    __shared__ u32 Ap[128][32];   // [co][k] packed, swizzled
    __shared__ u32 Bp[128][32];   // [px][k] packed, swizzled

    int b  = blockIdx.x;
    int n  = b & 7;               // batch -> XCD
    int q  = b >> 3;              // 0..79
    int cb = q & 3;
    int pt = q >> 2;              // 0..19
    int t  = threadIdx.x;
    int lane = t & 63;
    int w  = t >> 6;
    int wr = w >> 1, wc = w & 1;
    int px0 = pt * 128, co0 = cb * 128;
    const float* inN = in + (size_t)n * C_IN * PX;
    const u32*   XPn = XP ? (XP + (size_t)n * C_IN * PX) : nullptr;

    int sco = t >> 1;
    int skb = (t & 1) << 4;
    int spx = t & 127;
    int skk = (t >> 7) << 4;
    int gpx = px0 + spx;
    int sy  = gpx / 50;
    int sx  = gpx - sy * 50;
    bool pxok = (gpx < PX);
    const u32* wpA = WP + (size_t)(co0 + sco) * KDIM + skb;

    f32x4 acc[4][4];
#pragma unroll
    for (int i = 0; i < 4; ++i)
#pragma unroll
        for (int j = 0; j < 4; ++j) acc[i][j] = (f32x4)0.f;

    const int ro  = lane & 15;
    const int g8s = (lane >> 4) << 1;

    for (int cig = 0; cig < 16; ++cig) {
        int ci0 = cig << 5;
        for (int r = 0; r < 9; ++r) {
            int kstep = cig * 9 + r;
            {
                const u32* wp = wpA + kstep * 32;
                int rs = sco & 7;
#pragma unroll
                for (int qq = 0; qq < 4; ++qq) {
                    uint4 wv = *(const uint4*)(wp + qq * 4);
                    int slot = ((skb >> 2) + qq) ^ rs;
                    *(uint4*)&Ap[sco][slot << 2] = wv;
                }
            }
            {
                int ry = (r * 11) >> 5;
                int dy = ry - 1;
                int dx = r - ry * 3 - 1;
                int iy = sy + dy, ix = sx + dx;
                bool valid = pxok && ((unsigned)iy < 50u) && ((unsigned)ix < 50u);
                int off = iy * 50 + ix;
                u32 uu[16];
                if (XPn) {
                    const u32* bp = XPn + (size_t)(ci0 + skk) * PX + off;
#pragma unroll
                    for (int it = 0; it < 16; ++it)
                        uu[it] = valid ? bp[it * PX] : 0u;
                } else {
                    const float* bp = inN + (size_t)(ci0 + skk) * PX + off;
#pragma unroll
                    for (int it = 0; it < 16; ++it)
                        uu[it] = valid ? pack_split(bp[it * PX]) : 0u;
                }
                int rs = spx & 7;
#pragma unroll
                for (int qq = 0; qq < 4; ++qq) {
                    int slot = ((skk >> 2) + qq) ^ rs;
                    *(uint4*)&Bp[spx][slot << 2] = *(uint4*)&uu[qq * 4];
                }
            }
            __syncthreads();

            short8v aH[4], aL[4], bH[4], bL[4];
#pragma unroll
            for (int s = 0; s < 4; ++s) {
                {
                    int ra = wr * 64 + s * 16 + ro;
                    int rs = ra & 7;
                    u32 pa[8];
                    *(uint4*)&pa[0] = *(const uint4*)&Ap[ra][(g8s ^ rs) << 2];
                    *(uint4*)&pa[4] = *(const uint4*)&Ap[ra][((g8s + 1) ^ rs) << 2];
                    u32 h[4], l[4];
#pragma unroll
                    for (int w2 = 0; w2 < 4; ++w2) {
                        h[w2] = __builtin_amdgcn_perm(pa[2 * w2 + 1], pa[2 * w2], 0x07060302u);
                        l[w2] = __builtin_amdgcn_perm(pa[2 * w2 + 1], pa[2 * w2], 0x05040100u);
                    }
                    aH[s] = *(short8v*)h;
                    aL[s] = *(short8v*)l;
                }
                {
                    int rb = wc * 64 + s * 16 + ro;
                    int rs = rb & 7;
                    u32 pb[8];
                    *(uint4*)&pb[0] = *(const uint4*)&Bp[rb][(g8s ^ rs) << 2];
                    *(uint4*)&pb[4] = *(const uint4*)&Bp[rb][((g8s + 1) ^ rs) << 2];
                    u32 h[4], l[4];
#pragma unroll
                    for (int w2 = 0; w2 < 4; ++w2) {
                        h[w2] = __builtin_amdgcn_perm(pb[2 * w2 + 1], pb[2 * w2], 0x07060302u);
                        l[w2] = __builtin_amdgcn_perm(pb[2 * w2 + 1], pb[2 * w2], 0x05040100u);
                    }
                    bH[s] = *(short8v*)h;
                    bL[s] = *(short8v*)l;
                }
            }
#pragma unroll
            for (int i = 0; i < 4; ++i)
#pragma unroll
                for (int j = 0; j < 4; ++j) {
                    acc[i][j] = __builtin_amdgcn_mfma_f32_16x16x32_bf16(aH[i], bH[j], acc[i][j], 0, 0, 0);
                    acc[i][j] = __builtin_amdgcn_mfma_f32_16x16x32_bf16(aH[i], bL[j], acc[i][j], 0, 0, 0);
                    acc[i][j] = __builtin_amdgcn_mfma_f32_16x16x32_bf16(aL[i], bH[j], acc[i][j], 0, 0, 0);
                }
            __syncthreads();
        }
    }

    int coB  = co0 + wr * 64;
    int pxB  = px0 + wc * 64 + ro;
    int rowg = (lane >> 4) << 2;
#pragma unroll
    for (int i = 0; i < 4; ++i) {
#pragma unroll
        for (int rg = 0; rg < 4; ++rg) {
            int co = coB + i * 16 + rowg + rg;
            float bias = bc[co];
            float* dst = xout + ((size_t)n * C_IN + co) * PX;
#pragma unroll
            for (int j = 0; j < 4; ++j) {
                int px = pxB + j * 16;
                if (px < PX) dst[px] = fmaxf(acc[i][j][rg] + bias, 0.f);
            }
        }
    }
}

__device__ inline float readDim(const void* p) {
    int v = *(const int*)p;
    if (v > 0 && v <= 100000) return (float)v;
    return *(const float*)p;
}

// =================== 1x1 heads GEMM (fp32) + fused decode for batch 0 ===================
// 64-px tiles -> grid 320 (better occupancy). Per-element FMA order unchanged.
__global__ __launch_bounds__(256) void k_heads(const float* __restrict__ x,
                                               const float* __restrict__ Wreg,
                                               const float* __restrict__ breg,
                                               const float* __restrict__ Wcls,
                                               const float* __restrict__ bcls,
                                               float* __restrict__ out,
                                               float* __restrict__ wsScore,
                                               float* __restrict__ wsBox,
                                               const void* pih, const void* piw) {
    __shared__ float As[32][68];
    __shared__ float Bs[32][68];
    __shared__ float Hs[54][64];     // staged head outputs for decode (batch 0)
    int b  = blockIdx.x;
    int pt = b % 40, n = b / 40;
    int t  = threadIdx.x;
    int tx = t & 7, ty = t >> 3;     // ty 0..31 -> 2 channels each; tx -> 8 px
    int px0 = pt * 64;
    float acc[2][8];
#pragma unroll
    for (int i = 0; i < 2; ++i)
#pragma unroll
        for (int j = 0; j < 8; ++j) acc[i][j] = 0.f;

    for (int k0 = 0; k0 < 512; k0 += 32) {
        {
            int c   = t >> 2;            // 0..63
            int kkb = (t & 3) << 3;
            const float* src = nullptr;
            if (c < 36)      src = Wreg + (size_t)c * 512 + k0 + kkb;
            else if (c < 54) src = Wcls + (size_t)(c - 36) * 512 + k0 + kkb;
#pragma unroll
            for (int qq = 0; qq < 2; ++qq) {
                float4 wv = src ? *(const float4*)(src + qq * 4) : make_float4(0, 0, 0, 0);
                As[kkb + qq * 4 + 0][c] = wv.x;
                As[kkb + qq * 4 + 1][c] = wv.y;
                As[kkb + qq * 4 + 2][c] = wv.z;
                As[kkb + qq * 4 + 3][c] = wv.w;
            }
        }
        {
            int pxl = t & 63;
            int kk0 = (t >> 6) << 3;     // 0,8,16,24
            int px  = px0 + pxl;
#pragma unroll
            for (int it = 0; it < 8; ++it) {
                int kk = kk0 + it;
                float v = 0.f;
                if (px < PX) v = x[((size_t)n * 512 + k0 + kk) * PX + px];
                Bs[kk][pxl] = v;
            }
        }
        __syncthreads();
#pragma unroll 8
        for (int kk = 0; kk < 32; ++kk) {
            float a0 = As[kk][ty * 2], a1 = As[kk][ty * 2 + 1];
            float bb[8];
            *(float4*)&bb[0] = *(const float4*)&Bs[kk][tx * 8];
            *(float4*)&bb[4] = *(const float4*)&Bs[kk][tx * 8 + 4];
#pragma unroll
            for (int j = 0; j < 8; ++j) {
                acc[0][j] = fmaf(a0, bb[j], acc[0][j]);
                acc[1][j] = fmaf(a1, bb[j], acc[1][j]);
            }
        }
        __syncthreads();
    }
    int pxb = px0 + tx * 8;
#pragma unroll
    for (int i = 0; i < 2; ++i) {
        int c = ty * 2 + i;
        if (c >= 54) continue;
        float bias = (c < 36) ? breg[c] : bcls[c - 36];
        for (int j = 0; j < 8; ++j) {
            int px = pxb + j;
            if (px >= PX) break;
            float v = acc[i][j] + bias;
            if (c < 36)
                out[(size_t)n * 90000 + (size_t)px * 36 + c] = v;
            else
                out[OUT_SCORES + (size_t)n * 45000 + (size_t)px * 18 + (c - 36)] = v;
            if (n == 0) Hs[c][tx * 8 + j] = v;
        }
    }

    // ---- fused decode + anchors for batch 0 ----
    if (n == 0) {
        __syncthreads();
        float imgH = readDim(pih), imgW = readDim(piw);
        const float ratios[3] = {0.5f, 1.f, 2.f};
        const float scales[3] = {8.f, 16.f, 32.f};
        for (int idx = t; idx < 64 * 9; idx += 256) {
            int pxl = idx / 9;
            int a   = idx - pxl * 9;
            int px  = px0 + pxl;
            if (px >= PX) continue;
            int gi = px * 9 + a;
            int y = px / 50, xq = px - y * 50;
            float r = ratios[a / 3], s = scales[a % 3];
            float hh = 16.f * s * sqrtf(r);
            float wv = 16.f * s * sqrtf(1.f / r);
            float ay1 = y * 16.f + 8.f - 0.5f * hh;
            float ax1 = xq * 16.f + 8.f - 0.5f * wv;
            float ay2 = y * 16.f + 8.f + 0.5f * hh;
            float ax2 = xq * 16.f + 8.f + 0.5f * wv;
            *(float4*)(out + OUT_ANCH + (size_t)gi * 4) = make_float4(ay1, ax1, ay2, ax2);

            float l0 = Hs[a * 4 + 0][pxl];
            float l1 = Hs[a * 4 + 1][pxl];
            float l2 = Hs[a * 4 + 2][pxl];
            float l3 = Hs[a * 4 + 3][pxl];
            float s0 = Hs[36 + 2 * a][pxl];
            float s1 = Hs[37 + 2 * a][pxl];
            float fg = 1.f / (1.f + expf(s0 - s1));
            float ah = ay2 - ay1, aw = ax2 - ax1;
            float acy = ay1 + 0.5f * ah, acx = ax1 + 0.5f * aw;
            float cy = l0 * ah + acy;
            float cx = l1 * aw + acx;
            float bh = expf(l2) * ah;
            float bw = expf(l3) * aw;
            float b0 = cy - 0.5f * bh, b1 = cx - 0.5f * bw;
            float b2 = cy + 0.5f * bh, b3 = cx + 0.5f * bw;
            b0 = fminf(fmaxf(b0, 0.f), imgH);
            b1 = fminf(fmaxf(b1, 0.f), imgW);
            b2 = fminf(fmaxf(b2, 0.f), imgH);
            b3 = fminf(fmaxf(b3, 0.f), imgW);
            bool valid = ((b2 - b0) >= 16.f) && ((b3 - b1) >= 16.f);
            wsScore[gi] = valid ? fg : -INFINITY;
            *(float4*)(wsBox + (size_t)gi * 4) = make_float4(b0, b1, b2, b3);
        }
    }
}

// =================== select: top-6000 threshold + compaction -> global list ===================
__device__ inline u32 fkey(float s) {
    u32 u = __float_as_uint(s);
    return (u & 0x80000000u) ? ~u : (u | 0x80000000u);
}

__global__ __launch_bounds__(1024) void k_select(const float* __restrict__ score,
                                                 u64* __restrict__ list,
                                                 int* __restrict__ meta) {
    __shared__ u32 hist[4096];
    __shared__ int sB1, sB2, sM3, sNeed, sV;
    __shared__ u32 sT32;
    __shared__ int cHi, cTie;
    int t = threadIdx.x;
    const int NT = 1024;

    // ---- pass 1: top 12 bits ----
    for (int i = t; i < 4096; i += NT) hist[i] = 0;
    __syncthreads();
    for (int i = t; i < NA; i += NT) atomicAdd(&hist[fkey(score[i]) >> 20], 1u);
    __syncthreads();
    for (int off = 1; off < 4096; off <<= 1) {
        u32 v[4]; int c = 0;
        for (int bb = t; bb < 4096; bb += NT) { v[c++] = hist[bb] + ((bb + off < 4096) ? hist[bb + off] : 0u); }
        __syncthreads();
        c = 0;
        for (int bb = t; bb < 4096; bb += NT) hist[bb] = v[c++];
        __syncthreads();
    }
    for (int bb = t; bb < 4096; bb += NT) {
        u32 Sb  = hist[bb];
        u32 Sb1 = (bb < 4095) ? hist[bb + 1] : 0u;
        if (Sb >= PRE_NMS && Sb1 < PRE_NMS) sB1 = bb;
    }
    if (t == 0) sV = (int)hist[2048];
    __syncthreads();
    int B1 = sB1;
    int m1 = (B1 < 4095) ? (int)hist[B1 + 1] : 0;
    int V  = sV;
    __syncthreads();

    // ---- pass 2: mid 12 bits ----
    for (int i = t; i < 4096; i += NT) hist[i] = 0;
    __syncthreads();
    for (int i = t; i < NA; i += NT) {
        u32 key = fkey(score[i]);
        if ((int)(key >> 20) == B1) atomicAdd(&hist[(key >> 8) & 0xFFFu], 1u);
    }
    __syncthreads();
    for (int off = 1; off < 4096; off <<= 1) {
        u32 v[4]; int c = 0;
        for (int bb = t; bb < 4096; bb += NT) { v[c++] = hist[bb] + ((bb + off < 4096) ? hist[bb + off] : 0u); }
        __syncthreads();
        c = 0;
        for (int bb = t; bb < 4096; bb += NT) hist[bb] = v[c++];
        __syncthreads();
    }
    for (int bb = t; bb < 4096; bb += NT) {
        int Sb  = m1 + (int)hist[bb];
        int Sb1 = m1 + (int)((bb < 4095) ? hist[bb + 1] : 0u);
        if (Sb >= PRE_NMS && Sb1 < PRE_NMS) sB2 = bb;
    }
    __syncthreads();
    int B2 = sB2;
    int m2 = m1 + (int)((B2 < 4095) ? hist[B2 + 1] : 0u);
    u32 P24 = ((u32)B1 << 12) | (u32)B2;
    __syncthreads();

    // ---- pass 3: low 8 bits ----
    for (int i = t; i < 256; i += NT) hist[i] = 0;
    __syncthreads();
    for (int i = t; i < NA; i += NT) {
        u32 key = fkey(score[i]);
        if ((key >> 8) == P24) atomicAdd(&hist[key & 0xFFu], 1u);
    }
    __syncthreads();
    for (int off = 1; off < 256; off <<= 1) {
        u32 v[1]; int c = 0;
        for (int bb = t; bb < 256; bb += NT) { v[c++] = hist[bb] + ((bb + off < 256) ? hist[bb + off] : 0u); }
        __syncthreads();
        c = 0;
        for (int bb = t; bb < 256; bb += NT) hist[bb] = v[c++];
        __syncthreads();
    }
    for (int bb = t; bb < 256; bb += NT) {
        int Sb  = m2 + (int)hist[bb];
        int Sb1 = m2 + (int)((bb < 255) ? hist[bb + 1] : 0u);
        if (Sb >= PRE_NMS && Sb1 < PRE_NMS) {
            sM3   = m2 + (int)((bb < 255) ? hist[bb + 1] : 0u);
            sNeed = PRE_NMS - sM3;
            sT32  = (P24 << 8) | (u32)bb;
        }
    }
    if (t == 0) { cHi = 0; cTie = 0; meta[0] = (V < PRE_NMS) ? V : PRE_NMS; }
    __syncthreads();
    int m3 = sM3, need = sNeed;
    u32 T32 = sT32;

    // ---- compaction -> global list[0..5999]; pad 6000..8191 with 0 ----
    for (int i = t; i < NA; i += NT) {
        u32 key = fkey(score[i]);
        u64 comp = ((u64)key << 32) | (u64)(0xFFFFFFFFu - (u32)i);
        if (key > T32) {
            int p = atomicAdd(&cHi, 1);
            list[p] = comp;
        } else if (key == T32) {
            int p = atomicAdd(&cTie, 1);
            if (p < need) list[m3 + p] = comp;
        }
    }
    for (int i = PRE_NMS + t; i < 8192; i += NT) list[i] = 0ull;
}

// =================== presort: 4 blocks each bitonic-sort a 2048-chunk (k=2..2048) ===================
__global__ __launch_bounds__(1024) void k_presort(u64* __restrict__ list) {
    __shared__ u64 ls[2048];
    int t    = threadIdx.x;
    int base = blockIdx.x << 11;
    ls[t] = list[base + t];
    ls[t + 1024] = list[base + t + 1024];
    __syncthreads();
    for (int k = 2; k <= 2048; k <<= 1) {
        for (int j = k >> 1; j > 0; j >>= 1) {
            for (int i = t; i < 2048; i += 1024) {
                int ixj = i ^ j;
                if (ixj > i) {
                    u64 a = ls[i], b2 = ls[ixj];
                    bool desc = (((base + i) & k) == 0);
                    if (desc ? (a < b2) : (a > b2)) { ls[i] = b2; ls[ixj] = a; }
                }
            }
            __syncthreads();
        }
    }
    list[base + t] = ls[t];
    list[base + t + 1024] = ls[t + 1024];
}

// =================== merge (k=4096,8192) + greedy NMS, 128-wide chunks ===================
__global__ __launch_bounds__(1024) void k_mergenms(const u64* __restrict__ list,
                                                   const float* __restrict__ boxes,
                                                   const int* __restrict__ meta,
                                                   float* __restrict__ rois) {
    __shared__ u64 sb[8192];
    __shared__ float kb[POST_NMS][4];
    __shared__ float cb4[128][4];
    __shared__ u32 Kw[128][4];       // kill bits: words 0..3 cover j=0..127
    __shared__ u32 supA[128];
    __shared__ int sKept;
    int t = threadIdx.x;
    const int NT = 1024;

    for (int i = t; i < 8192; i += NT) sb[i] = list[i];
    __syncthreads();

    // remaining bitonic phases
    for (int k = 4096; k <= 8192; k <<= 1) {
        for (int j = k >> 1; j > 0; j >>= 1) {
            for (int i = t; i < 8192; i += NT) {
                int ixj = i ^ j;
                if (ixj > i) {
                    u64 a = sb[i], bv = sb[ixj];
                    bool desc = ((i & k) == 0);
                    if (desc ? (a < bv) : (a > bv)) { sb[i] = bv; sb[ixj] = a; }
                }
            }
            __syncthreads();
        }
    }

    int keepN = meta[0];
    if (t == 0) sKept = 0;
    __syncthreads();

    int s = t >> 3, g = t & 7;   // 128 cands x 8 groups
    for (int c0 = 0; c0 < PRE_NMS; c0 += 128) {
        if (sKept >= POST_NMS) break;
        // load 128 candidate boxes
        if (t < 128) {
            u32 bidx = 0xFFFFFFFFu - (u32)sb[c0 + t];
            if (bidx >= NA) bidx = 0;            // pad-safe
            float4 bx = *(const float4*)(boxes + (size_t)bidx * 4);
            cb4[t][0] = bx.x; cb4[t][1] = bx.y; cb4[t][2] = bx.z; cb4[t][3] = bx.w;
            Kw[t][0] = 0; Kw[t][1] = 0; Kw[t][2] = 0; Kw[t][3] = 0;
            supA[t] = 0;
        }
        __syncthreads();

        float y1 = cb4[s][0], x1 = cb4[s][1], y2 = cb4[s][2], x2 = cb4[s][3];
        float area = (y2 - y1) * (x2 - x1);

        // pairwise kill bits: this thread covers j = g*16 .. g*16+15 (one u32 half-word range)
        u32 kbits = 0;
#pragma unroll
        for (int qq = 0; qq < 16; ++qq) {
            int j = g * 16 + qq;
            if (j > s) {
                float jy1 = cb4[j][0], jx1 = cb4[j][1], jy2 = cb4[j][2], jx2 = cb4[j][3];
                float yy1 = fmaxf(y1, jy1), xx1 = fmaxf(x1, jx1);
                float yy2 = fminf(y2, jy2), xx2 = fminf(x2, jx2);
                float inter = fmaxf(yy2 - yy1, 0.f) * fmaxf(xx2 - xx1, 0.f);
                float ja = (jy2 - jy1) * (jx2 - jx1);
                float iou = inter / (area + ja - inter + 1e-12f);
                if (iou > 0.7f) kbits |= 1u << (j & 31);
            }
        }
        if (kbits) atomicOr(&Kw[s][g >> 1], kbits);

        // phase A: cand s vs already-kept, split 8 ways
        int kept0 = sKept;
        bool supf = false;
        for (int jj = g; jj < kept0; jj += 8) {
            float ky1 = kb[jj][0], kx1 = kb[jj][1], ky2 = kb[jj][2], kx2 = kb[jj][3];
            float yy1 = fmaxf(ky1, y1), xx1 = fmaxf(kx1, x1);
            float yy2 = fminf(ky2, y2), xx2 = fminf(kx2, x2);
            float inter = fmaxf(yy2 - yy1, 0.f) * fmaxf(xx2 - xx1, 0.f);
            float karea = (ky2 - ky1) * (kx2 - kx1);
            float iou = inter / (karea + area - inter + 1e-12f);
            if (iou > 0.7f) { supf = true; break; }
        }
        if (supf) atomicOr(&supA[s], 1u);
        __syncthreads();

        // serial greedy over the 128-chunk (LDS reads only)
        if (t == 0) {
            u64 m0 = 0, m1 = 0;
            int kept = sKept;
            for (int s2 = 0; s2 < 128 && kept < POST_NMS; ++s2) {
                if (c0 + s2 >= keepN) continue;
                if (supA[s2]) continue;
                bool supm = (s2 < 64) ? ((m0 >> s2) & 1ull) : ((m1 >> (s2 - 64)) & 1ull);
                if (supm) continue;
                kb[kept][0] = cb4[s2][0]; kb[kept][1] = cb4[s2][1];
                kb[kept][2] = cb4[s2][2]; kb[kept][3] = cb4[s2][3];
                *(float4*)(rois + (size_t)kept * 4) =
                    make_float4(cb4[s2][0], cb4[s2][1], cb4[s2][2], cb4[s2][3]);
                kept++;
                m0 |= ((u64)Kw[s2][1] << 32) | (u64)Kw[s2][0];
                m1 |= ((u64)Kw[s2][3] << 32) | (u64)Kw[s2][2];
            }
            sKept = kept;
        }
        __syncthreads();
    }

    int kf = sKept;
    for (int r = kf * 4 + t; r < POST_NMS * 4; r += NT) rois[r] = 0.f;
}

// =================== launcher ===================
extern "C" void kernel_launch(void* const* d_in, const int* in_sizes, int n_in,
                              void* d_out, int out_size, void* d_ws, size_t ws_size,
                              hipStream_t stream) {
    const float* feat = (const float*)d_in[0];
    const float* Wc   = (const float*)d_in[1];
    const float* bc   = (const float*)d_in[2];
    const float* Wcls = (const float*)d_in[3];
    const float* bcls = (const float*)d_in[4];
    const float* Wreg = (const float*)d_in[5];
    const float* breg = (const float*)d_in[6];
    const void* pih   = d_in[7];
    const void* piw   = d_in[8];
    float* out = (float*)d_out;
    float* ws  = (float*)d_ws;

    u32* WP   = (u32*)(ws + WS_WP);
    u64* list = (u64*)(ws + WS_LIST);
    int* meta = (int*)(ws + WS_META);
    bool haveXP = (ws_size >= (size_t)WS_END * sizeof(float));
    u32* XP = haveXP ? (u32*)(ws + WS_XP) : nullptr;

    int prepItems = NW_ELEMS + (haveXP ? NX_ELEMS : 0);
    hipLaunchKernelGGL(k_prep, dim3((prepItems + 255) / 256), dim3(256), 0, stream, Wc, feat, WP, XP);
    hipLaunchKernelGGL(k_conv3, dim3(640), dim3(256), 0, stream, feat, XP, WP, bc, ws + WS_X);
    hipLaunchKernelGGL(k_heads, dim3(320), dim3(256), 0, stream, ws + WS_X, Wreg, breg, Wcls, bcls,
                       out, ws + WS_SCORE, ws + WS_BOX, pih, piw);
    hipLaunchKernelGGL(k_select, dim3(1), dim3(1024), 0, stream, ws + WS_SCORE, list, meta);
    hipLaunchKernelGGL(k_presort, dim3(4), dim3(1024), 0, stream, list);
    hipLaunchKernelGGL(k_mergenms, dim3(1), dim3(1024), 0, stream, list, ws + WS_BOX, meta, out + OUT_ROIS);
}